// Round 1
// baseline (3705.394 us; speedup 1.0000x reference)
//
#include <hip/hip_runtime.h>
#include <hip/hip_bf16.h>
#include <float.h>
#include <math.h>

#define NB 4
#define NN 8192
#define FF 64
#define MM 2048
#define KK 32
#define HH 64

// ---------------- Kernel 1: exact FPS, one block per cloud ----------------
__global__ __launch_bounds__(1024) void fps_kernel(
    const float* __restrict__ pos,
    int* __restrict__ samp,
    float* __restrict__ centers_out,
    float* __restrict__ batch_out)
{
    const int b = blockIdx.x;
    const float* pb = pos + (size_t)b * NN * 3;
    const int tid = threadIdx.x;

    float px[8], py[8], pz[8], dist[8];
#pragma unroll
    for (int i = 0; i < 8; ++i) {
        int g = tid + i * 1024;
        px[i] = pb[g * 3 + 0];
        py[i] = pb[g * 3 + 1];
        pz[i] = pb[g * 3 + 2];
        dist[i] = INFINITY;
    }

    __shared__ float redv[16];
    __shared__ int   redi[16];
    __shared__ int   winner;

    int cur = 0;
    for (int s = 0; s < MM; ++s) {
        // emit current index (matches ref: idx[s] emitted before update)
        if (tid == 0) samp[b * MM + s] = cur;
        if (tid == 1) batch_out[b * MM + s] = (float)b;
        if (tid < 3) centers_out[((size_t)b * MM + s) * 3 + tid] = pb[cur * 3 + tid];
        if (s == MM - 1) break;   // last argmax unused

        float lx = pb[cur * 3 + 0];
        float ly = pb[cur * 3 + 1];
        float lz = pb[cur * 3 + 2];

        float bv = -INFINITY;
        int   bi = 0x7fffffff;
#pragma unroll
        for (int i = 0; i < 8; ++i) {
            // exact ref arithmetic: (p - last)^2 summed as ((x+y)+z), no FMA
            float dx = __fsub_rn(px[i], lx);
            float dy = __fsub_rn(py[i], ly);
            float dz = __fsub_rn(pz[i], lz);
            float d  = __fadd_rn(__fadd_rn(__fmul_rn(dx, dx), __fmul_rn(dy, dy)),
                                 __fmul_rn(dz, dz));
            float nd = fminf(dist[i], d);
            dist[i] = nd;
            // ascending gid scan + strict > == first-max tie-break
            if (nd > bv) { bv = nd; bi = tid + i * 1024; }
        }
        // wave64 (val,idx) argmax reduce, tie -> lower index
#pragma unroll
        for (int off = 32; off >= 1; off >>= 1) {
            float ov = __shfl_xor(bv, off);
            int   oi = __shfl_xor(bi, off);
            if (ov > bv || (ov == bv && oi < bi)) { bv = ov; bi = oi; }
        }
        const int w = tid >> 6;
        if ((tid & 63) == 0) { redv[w] = bv; redi[w] = bi; }
        __syncthreads();
        if (tid < 64) {
            float v = (tid < 16) ? redv[tid] : -INFINITY;
            int  ii = (tid < 16) ? redi[tid] : 0x7fffffff;
#pragma unroll
            for (int off = 8; off >= 1; off >>= 1) {
                float ov = __shfl_xor(v, off);
                int   oi = __shfl_xor(ii, off);
                if (ov > v || (ov == v && oi < ii)) { v = ov; ii = oi; }
            }
            if (tid == 0) winner = ii;
        }
        __syncthreads();
        cur = winner;
    }
}

// ---------------- Kernel 2: radius-KNN, one wave per center ----------------
#define CAP 256
__global__ __launch_bounds__(256) void knn_kernel(
    const float* __restrict__ pos,
    const int* __restrict__ samp,
    int* __restrict__ nbr,
    int* __restrict__ cntbuf)
{
    const int wave = threadIdx.x >> 6;
    const int lane = threadIdx.x & 63;
    const int c = blockIdx.x * 4 + wave;          // global center id
    const int b = c >> 11;                         // c / MM
    const float* pb = pos + (size_t)b * NN * 3;

    __shared__ float sd2[4][CAP];
    __shared__ int   sid[4][CAP];

    const int ctr = samp[c];
    const float cx = pb[ctr * 3 + 0];
    const float cy = pb[ctr * 3 + 1];
    const float cz = pb[ctr * 3 + 2];
    const float R2 = (float)(0.1 * 0.1);   // same fp32 constant as the ref compare

    int cnt = 0;
    for (int r = 0; r < NN / 64; ++r) {
        const int g = r * 64 + lane;
        float dx = __fsub_rn(cx, pb[g * 3 + 0]);
        float dy = __fsub_rn(cy, pb[g * 3 + 1]);
        float dz = __fsub_rn(cz, pb[g * 3 + 2]);
        float d2 = __fadd_rn(__fadd_rn(__fmul_rn(dx, dx), __fmul_rn(dy, dy)),
                             __fmul_rn(dz, dz));
        const bool pred = (d2 <= R2);
        const unsigned long long mask = __ballot(pred);
        const int before = __popcll(mask & ((1ull << lane) - 1ull));
        if (pred) {
            const int slot = cnt + before;
            if (slot < CAP) { sd2[wave][slot] = d2; sid[wave][slot] = g; }
        }
        cnt += __popcll(mask);
    }
    if (cnt > CAP) cnt = CAP;
    __syncthreads();

    // rank-select the K smallest (tie -> lower point index) == lax.top_k set
    for (int ci = lane; ci < cnt; ci += 64) {
        const float dc = sd2[wave][ci];
        const int   ic = sid[wave][ci];
        int rank = 0;
        for (int j = 0; j < cnt; ++j) {
            const float dj = sd2[wave][j];
            const int   ij = sid[wave][j];
            rank += (dj < dc || (dj == dc && ij < ic)) ? 1 : 0;
        }
        if (rank < KK) nbr[c * KK + rank] = ic;
    }
    if (lane == 0) cntbuf[c] = (cnt < KK) ? cnt : KK;
}

// ---------------- Kernel 3: gather + MLP + max-pool, one wave per center ----
__global__ __launch_bounds__(256) void mlp_kernel(
    const float* __restrict__ x,
    const float* __restrict__ pos,
    const float* __restrict__ W1,
    const float* __restrict__ b1,
    const float* __restrict__ W2,
    const float* __restrict__ b2,
    const int* __restrict__ nbr,
    const int* __restrict__ cntbuf,
    const float* __restrict__ centers,
    float* __restrict__ out)
{
    __shared__ float WT[64 * 68];         // W1^T then W2^T (stride 68)
    __shared__ float featL[4][32 * 68];   // per-wave feat rows, later h1 rows

    const int tid = threadIdx.x, wave = tid >> 6, lane = tid & 63;
    const int c = blockIdx.x * 4 + wave;
    const int b = c >> 11;
    const int cnt = cntbuf[c];

    // stage W1^T: WT[h*68 + i] = W1[i*64 + h]; zero the pad column
    for (int idx = tid; idx < 67 * 64; idx += 256) {
        const int i = idx >> 6, h = idx & 63;
        WT[h * 68 + i] = W1[idx];
    }
    if (tid < 64) WT[tid * 68 + 67] = 0.0f;

    // stage feat rows for this wave's center (coalesced: one x-row per iter)
    const float ctr0 = centers[c * 3 + 0];
    const float ctr1 = centers[c * 3 + 1];
    const float ctr2 = centers[c * 3 + 2];
    for (int k = 0; k < cnt; ++k) {
        const int j = nbr[c * KK + k];
        featL[wave][k * 68 + lane] = x[((size_t)b * NN + j) * FF + lane];
        if (lane < 3) {
            const float pj = pos[((size_t)b * NN + j) * 3 + lane];
            const float ci = (lane == 0) ? ctr0 : ((lane == 1) ? ctr1 : ctr2);
            featL[wave][k * 68 + 64 + lane] = __fsub_rn(pj, ci);
        }
        if (lane == 3) featL[wave][k * 68 + 67] = 0.0f;
    }
    __syncthreads();

    // layer 1: lane = output channel h; W1 column cached in registers
    float w[68];
#pragma unroll
    for (int i4 = 0; i4 < 17; ++i4) {
        const float4 v = *(const float4*)&WT[lane * 68 + i4 * 4];
        w[i4 * 4 + 0] = v.x; w[i4 * 4 + 1] = v.y;
        w[i4 * 4 + 2] = v.z; w[i4 * 4 + 3] = v.w;
    }
    const float bias1 = b1[lane];
    for (int k = 0; k < cnt; ++k) {
        float acc = bias1;
#pragma unroll
        for (int i4 = 0; i4 < 17; ++i4) {
            const float4 f = *(const float4*)&featL[wave][k * 68 + i4 * 4];
            acc = fmaf(f.x, w[i4 * 4 + 0], acc);
            acc = fmaf(f.y, w[i4 * 4 + 1], acc);
            acc = fmaf(f.z, w[i4 * 4 + 2], acc);
            acc = fmaf(f.w, w[i4 * 4 + 3], acc);
        }
        // overwrite row k with h1 (reads of row k already issued in-order)
        featL[wave][k * 68 + lane] = fmaxf(acc, 0.0f);
    }
    __syncthreads();

    // restage WT with W2^T
    for (int idx = tid; idx < 64 * 64; idx += 256) {
        const int i = idx >> 6, h = idx & 63;
        WT[h * 68 + i] = W2[idx];
    }
    __syncthreads();

#pragma unroll
    for (int i4 = 0; i4 < 16; ++i4) {
        const float4 v = *(const float4*)&WT[lane * 68 + i4 * 4];
        w[i4 * 4 + 0] = v.x; w[i4 * 4 + 1] = v.y;
        w[i4 * 4 + 2] = v.z; w[i4 * 4 + 3] = v.w;
    }
    const float bias2 = b2[lane];
    float m = -INFINITY;
    for (int k = 0; k < cnt; ++k) {
        float acc = bias2;
#pragma unroll
        for (int i4 = 0; i4 < 16; ++i4) {
            const float4 f = *(const float4*)&featL[wave][k * 68 + i4 * 4];
            acc = fmaf(f.x, w[i4 * 4 + 0], acc);
            acc = fmaf(f.y, w[i4 * 4 + 1], acc);
            acc = fmaf(f.z, w[i4 * 4 + 2], acc);
            acc = fmaf(f.w, w[i4 * 4 + 3], acc);
        }
        m = fmaxf(m, fmaxf(acc, 0.0f));
    }
    out[(size_t)c * HH + lane] = (cnt > 0) ? m : 0.0f;
}

extern "C" void kernel_launch(void* const* d_in, const int* in_sizes, int n_in,
                              void* d_out, int out_size, void* d_ws, size_t ws_size,
                              hipStream_t stream) {
    const float* x   = (const float*)d_in[0];   // [B*N, 64]
    const float* pos = (const float*)d_in[1];   // [B*N, 3]
    const float* W1  = (const float*)d_in[3];   // [67, 64]
    const float* b1  = (const float*)d_in[4];   // [64]
    const float* W2  = (const float*)d_in[5];   // [64, 64]
    const float* b2  = (const float*)d_in[6];   // [64]

    float* out        = (float*)d_out;                       // [B*M, 64]
    float* centers_out = out + (size_t)NB * MM * HH;         // [B*M, 3]
    float* batch_out   = centers_out + (size_t)NB * MM * 3;  // [B*M]

    char* ws = (char*)d_ws;
    int* samp   = (int*)ws;                          // [B*M]
    int* cntbuf = (int*)(ws + (size_t)NB * MM * 4);  // [B*M]
    int* nbr    = (int*)(ws + (size_t)2 * NB * MM * 4); // [B*M, K]

    fps_kernel<<<NB, 1024, 0, stream>>>(pos, samp, centers_out, batch_out);
    knn_kernel<<<(NB * MM) / 4, 256, 0, stream>>>(pos, samp, nbr, cntbuf);
    mlp_kernel<<<(NB * MM) / 4, 256, 0, stream>>>(x, pos, W1, b1, W2, b2,
                                                  nbr, cntbuf, centers_out, out);
}

// Round 2
// 3601.242 us; speedup vs baseline: 1.0289x; 1.0289x over previous
//
#include <hip/hip_runtime.h>
#include <hip/hip_bf16.h>
#include <float.h>
#include <math.h>

#define NB 4
#define NN 8192
#define FF 64
#define MM 2048
#define KK 32
#define HH 64

#define FT 512          // fps threads
#define PPT 16          // points per thread (FT*PPT == NN)

// DPP-based wave64 argmax (value, index), tie -> lower index.
// After the 6 steps, lane 63 holds the full-wave winner.
// old = identity (-inf, INT_MAX) so masked/invalid lanes never win.
#define DPP_ARGMAX_STEP(bv, bi, ctrl, rmask)                                   \
    {                                                                          \
        int _ovb = __builtin_amdgcn_update_dpp((int)0xff800000,                \
                        __float_as_int(bv), (ctrl), (rmask), 0xf, false);      \
        int _oi  = __builtin_amdgcn_update_dpp((int)0x7fffffff,                \
                        (bi), (ctrl), (rmask), 0xf, false);                    \
        float _ov = __int_as_float(_ovb);                                      \
        if (_ov > (bv) || (_ov == (bv) && _oi < (bi))) { (bv) = _ov; (bi) = _oi; } \
    }

// ---------------- Kernel 1: exact FPS, one block per cloud ----------------
__global__ __launch_bounds__(FT) void fps_kernel(
    const float* __restrict__ pos,
    int* __restrict__ samp,
    float* __restrict__ centers_out,
    float* __restrict__ batch_out)
{
    const int b = blockIdx.x;
    const float* pb = pos + (size_t)b * NN * 3;
    const int tid = threadIdx.x;
    const int wv  = tid >> 6;
    const int lane = tid & 63;

    __shared__ float slotv[2][8];
    __shared__ int   sloti[2][8];

    float px[PPT], py[PPT], pz[PPT], dist[PPT];
#pragma unroll
    for (int i = 0; i < PPT; ++i) {
        const int g = tid + i * FT;
        px[i] = pb[g * 3 + 0];
        py[i] = pb[g * 3 + 1];
        pz[i] = pb[g * 3 + 2];
        dist[i] = INFINITY;
    }

    // prefill batch output once (constant per cloud)
    for (int j = tid; j < MM; j += FT) batch_out[b * MM + j] = (float)b;

    int   cur = 0;
    float lx = pb[0], ly = pb[1], lz = pb[2];

    for (int s = 0; s < MM; ++s) {
        if (tid == 0) {
            samp[b * MM + s] = cur;
            centers_out[((size_t)b * MM + s) * 3 + 0] = lx;
            centers_out[((size_t)b * MM + s) * 3 + 1] = ly;
            centers_out[((size_t)b * MM + s) * 3 + 2] = lz;
        }
        if (s == MM - 1) break;   // last argmax unused by the reference

        float bv = -INFINITY;
        int   bi = 0x7fffffff;
#pragma unroll
        for (int i = 0; i < PPT; ++i) {
            // exact ref arithmetic: ((dx*dx + dy*dy) + dz*dz), no FMA contraction
            float dx = __fsub_rn(px[i], lx);
            float dy = __fsub_rn(py[i], ly);
            float dz = __fsub_rn(pz[i], lz);
            float d  = __fadd_rn(__fadd_rn(__fmul_rn(dx, dx), __fmul_rn(dy, dy)),
                                 __fmul_rn(dz, dz));
            float nd = fminf(dist[i], d);
            dist[i] = nd;
            // ascending g within thread + strict > == first-max tie-break
            if (nd > bv) { bv = nd; bi = tid + i * FT; }
        }

        // wave64 argmax via DPP: row_shr 1,2,4,8 then bcast15 (rows 1,3),
        // bcast31 (rows 2,3). lane 63 ends with the wave winner.
        DPP_ARGMAX_STEP(bv, bi, 0x111, 0xf);   // row_shr:1
        DPP_ARGMAX_STEP(bv, bi, 0x112, 0xf);   // row_shr:2
        DPP_ARGMAX_STEP(bv, bi, 0x114, 0xf);   // row_shr:4
        DPP_ARGMAX_STEP(bv, bi, 0x118, 0xf);   // row_shr:8
        DPP_ARGMAX_STEP(bv, bi, 0x142, 0xa);   // row_bcast:15 -> rows 1,3
        DPP_ARGMAX_STEP(bv, bi, 0x143, 0xc);   // row_bcast:31 -> rows 2,3

        const int par = s & 1;
        if (lane == 63) { slotv[par][wv] = bv; sloti[par][wv] = bi; }
        __syncthreads();

        // every thread redundantly scans the 8 per-wave winners (broadcast reads)
        float wbv = -INFINITY;
        int   wbi = 0x7fffffff;
#pragma unroll
        for (int w = 0; w < 8; ++w) {
            const float v  = slotv[par][w];
            const int   i2 = sloti[par][w];
            if (v > wbv || (v == wbv && i2 < wbi)) { wbv = v; wbi = i2; }
        }
        cur = wbi;
        lx = pb[cur * 3 + 0];
        ly = pb[cur * 3 + 1];
        lz = pb[cur * 3 + 2];
    }
}

// ---------------- Kernel 2: radius-KNN, one wave per center ----------------
#define CAP 256
__global__ __launch_bounds__(256) void knn_kernel(
    const float* __restrict__ pos,
    const int* __restrict__ samp,
    int* __restrict__ nbr,
    int* __restrict__ cntbuf)
{
    const int wave = threadIdx.x >> 6;
    const int lane = threadIdx.x & 63;
    const int c = blockIdx.x * 4 + wave;          // global center id
    const int b = c >> 11;                         // c / MM
    const float* pb = pos + (size_t)b * NN * 3;

    __shared__ float sd2[4][CAP];
    __shared__ int   sid[4][CAP];

    const int ctr = samp[c];
    const float cx = pb[ctr * 3 + 0];
    const float cy = pb[ctr * 3 + 1];
    const float cz = pb[ctr * 3 + 2];
    const float R2 = (float)(0.1 * 0.1);

    int cnt = 0;
    for (int r = 0; r < NN / 64; ++r) {
        const int g = r * 64 + lane;
        float dx = __fsub_rn(cx, pb[g * 3 + 0]);
        float dy = __fsub_rn(cy, pb[g * 3 + 1]);
        float dz = __fsub_rn(cz, pb[g * 3 + 2]);
        float d2 = __fadd_rn(__fadd_rn(__fmul_rn(dx, dx), __fmul_rn(dy, dy)),
                             __fmul_rn(dz, dz));
        const bool pred = (d2 <= R2);
        const unsigned long long mask = __ballot(pred);
        const int before = __popcll(mask & ((1ull << lane) - 1ull));
        if (pred) {
            const int slot = cnt + before;
            if (slot < CAP) { sd2[wave][slot] = d2; sid[wave][slot] = g; }
        }
        cnt += __popcll(mask);
    }
    if (cnt > CAP) cnt = CAP;
    __syncthreads();

    // rank-select the K smallest (tie -> lower point index) == lax.top_k set
    for (int ci = lane; ci < cnt; ci += 64) {
        const float dc = sd2[wave][ci];
        const int   ic = sid[wave][ci];
        int rank = 0;
        for (int j = 0; j < cnt; ++j) {
            const float dj = sd2[wave][j];
            const int   ij = sid[wave][j];
            rank += (dj < dc || (dj == dc && ij < ic)) ? 1 : 0;
        }
        if (rank < KK) nbr[c * KK + rank] = ic;
    }
    if (lane == 0) cntbuf[c] = (cnt < KK) ? cnt : KK;
}

// ---------------- Kernel 3: gather + MLP + max-pool, one wave per center ----
__global__ __launch_bounds__(256) void mlp_kernel(
    const float* __restrict__ x,
    const float* __restrict__ pos,
    const float* __restrict__ W1,
    const float* __restrict__ b1,
    const float* __restrict__ W2,
    const float* __restrict__ b2,
    const int* __restrict__ nbr,
    const int* __restrict__ cntbuf,
    const float* __restrict__ centers,
    float* __restrict__ out)
{
    __shared__ float WT[64 * 68];         // W1^T then W2^T (stride 68)
    __shared__ float featL[4][32 * 68];   // per-wave feat rows, later h1 rows

    const int tid = threadIdx.x, wave = tid >> 6, lane = tid & 63;
    const int c = blockIdx.x * 4 + wave;
    const int b = c >> 11;
    const int cnt = cntbuf[c];

    for (int idx = tid; idx < 67 * 64; idx += 256) {
        const int i = idx >> 6, h = idx & 63;
        WT[h * 68 + i] = W1[idx];
    }
    if (tid < 64) WT[tid * 68 + 67] = 0.0f;

    const float ctr0 = centers[c * 3 + 0];
    const float ctr1 = centers[c * 3 + 1];
    const float ctr2 = centers[c * 3 + 2];
    for (int k = 0; k < cnt; ++k) {
        const int j = nbr[c * KK + k];
        featL[wave][k * 68 + lane] = x[((size_t)b * NN + j) * FF + lane];
        if (lane < 3) {
            const float pj = pos[((size_t)b * NN + j) * 3 + lane];
            const float ci = (lane == 0) ? ctr0 : ((lane == 1) ? ctr1 : ctr2);
            featL[wave][k * 68 + 64 + lane] = __fsub_rn(pj, ci);
        }
        if (lane == 3) featL[wave][k * 68 + 67] = 0.0f;
    }
    __syncthreads();

    float w[68];
#pragma unroll
    for (int i4 = 0; i4 < 17; ++i4) {
        const float4 v = *(const float4*)&WT[lane * 68 + i4 * 4];
        w[i4 * 4 + 0] = v.x; w[i4 * 4 + 1] = v.y;
        w[i4 * 4 + 2] = v.z; w[i4 * 4 + 3] = v.w;
    }
    const float bias1 = b1[lane];
    for (int k = 0; k < cnt; ++k) {
        float acc = bias1;
#pragma unroll
        for (int i4 = 0; i4 < 17; ++i4) {
            const float4 f = *(const float4*)&featL[wave][k * 68 + i4 * 4];
            acc = fmaf(f.x, w[i4 * 4 + 0], acc);
            acc = fmaf(f.y, w[i4 * 4 + 1], acc);
            acc = fmaf(f.z, w[i4 * 4 + 2], acc);
            acc = fmaf(f.w, w[i4 * 4 + 3], acc);
        }
        featL[wave][k * 68 + lane] = fmaxf(acc, 0.0f);
    }
    __syncthreads();

    for (int idx = tid; idx < 64 * 64; idx += 256) {
        const int i = idx >> 6, h = idx & 63;
        WT[h * 68 + i] = W2[idx];
    }
    __syncthreads();

#pragma unroll
    for (int i4 = 0; i4 < 16; ++i4) {
        const float4 v = *(const float4*)&WT[lane * 68 + i4 * 4];
        w[i4 * 4 + 0] = v.x; w[i4 * 4 + 1] = v.y;
        w[i4 * 4 + 2] = v.z; w[i4 * 4 + 3] = v.w;
    }
    const float bias2 = b2[lane];
    float m = -INFINITY;
    for (int k = 0; k < cnt; ++k) {
        float acc = bias2;
#pragma unroll
        for (int i4 = 0; i4 < 16; ++i4) {
            const float4 f = *(const float4*)&featL[wave][k * 68 + i4 * 4];
            acc = fmaf(f.x, w[i4 * 4 + 0], acc);
            acc = fmaf(f.y, w[i4 * 4 + 1], acc);
            acc = fmaf(f.z, w[i4 * 4 + 2], acc);
            acc = fmaf(f.w, w[i4 * 4 + 3], acc);
        }
        m = fmaxf(m, fmaxf(acc, 0.0f));
    }
    out[(size_t)c * HH + lane] = (cnt > 0) ? m : 0.0f;
}

extern "C" void kernel_launch(void* const* d_in, const int* in_sizes, int n_in,
                              void* d_out, int out_size, void* d_ws, size_t ws_size,
                              hipStream_t stream) {
    const float* x   = (const float*)d_in[0];   // [B*N, 64]
    const float* pos = (const float*)d_in[1];   // [B*N, 3]
    const float* W1  = (const float*)d_in[3];   // [67, 64]
    const float* b1  = (const float*)d_in[4];   // [64]
    const float* W2  = (const float*)d_in[5];   // [64, 64]
    const float* b2  = (const float*)d_in[6];   // [64]

    float* out         = (float*)d_out;                      // [B*M, 64]
    float* centers_out = out + (size_t)NB * MM * HH;         // [B*M, 3]
    float* batch_out   = centers_out + (size_t)NB * MM * 3;  // [B*M]

    char* ws = (char*)d_ws;
    int* samp   = (int*)ws;                             // [B*M]
    int* cntbuf = (int*)(ws + (size_t)NB * MM * 4);     // [B*M]
    int* nbr    = (int*)(ws + (size_t)2 * NB * MM * 4); // [B*M, K]

    fps_kernel<<<NB, FT, 0, stream>>>(pos, samp, centers_out, batch_out);
    knn_kernel<<<(NB * MM) / 4, 256, 0, stream>>>(pos, samp, nbr, cntbuf);
    mlp_kernel<<<(NB * MM) / 4, 256, 0, stream>>>(x, pos, W1, b1, W2, b2,
                                                  nbr, cntbuf, centers_out, out);
}

// Round 3
// 2926.594 us; speedup vs baseline: 1.2661x; 1.2305x over previous
//
#include <hip/hip_runtime.h>
#include <hip/hip_bf16.h>
#include <float.h>
#include <math.h>

#define NB 4
#define NN 8192
#define FF 64
#define MM 2048
#define KK 32
#define HH 64

#define FT 512          // fps threads (8 waves)
#define PPT 16          // points per thread (FT*PPT == NN)

// DPP-based wave64 argmax (value, index), tie -> lower index.
// After the 6 steps, lane 63 holds the full-wave winner. (verified round 2)
#define DPP_ARGMAX_STEP(bv, bi, ctrl, rmask)                                   \
    {                                                                          \
        int _ovb = __builtin_amdgcn_update_dpp((int)0xff800000,                \
                        __float_as_int(bv), (ctrl), (rmask), 0xf, false);      \
        int _oi  = __builtin_amdgcn_update_dpp((int)0x7fffffff,                \
                        (bi), (ctrl), (rmask), 0xf, false);                    \
        float _ov = __int_as_float(_ovb);                                      \
        if (_ov > (bv) || (_ov == (bv) && _oi < (bi))) { (bv) = _ov; (bi) = _oi; } \
    }

// comparator for (value, idxbits) packed in float2: max value, tie -> lower idx
__device__ __forceinline__ float2 argmax2(float2 a, float2 b) {
    const int ia = __float_as_int(a.y), ib = __float_as_int(b.y);
    return (b.x > a.x || (b.x == a.x && ib < ia)) ? b : a;
}

// ---------------- Kernel 1: exact FPS, one block per cloud ----------------
__global__ __launch_bounds__(FT) void fps_kernel(
    const float* __restrict__ pos,
    int* __restrict__ samp,
    float* __restrict__ centers_out,
    float* __restrict__ batch_out)
{
    __shared__ float xs[NN], ys[NN], zs[NN];   // 96 KB SoA point store
    __shared__ float2 slots[2][8];             // parity-buffered per-wave winners

    const int b = blockIdx.x;
    const float* pb = pos + (size_t)b * NN * 3;
    const int tid = threadIdx.x;
    const int wv  = tid >> 6;
    const int lane = tid & 63;

    // stage points: each thread reads 16 consecutive float3s (contiguous 192B
    // per 16-lane group -> coalesced enough, one-time cost)
    for (int j = tid; j < NN; j += FT) {
        xs[j] = pb[j * 3 + 0];
        ys[j] = pb[j * 3 + 1];
        zs[j] = pb[j * 3 + 2];
    }
    // prefill batch output once (constant per cloud)
    for (int j = tid; j < MM; j += FT) batch_out[b * MM + j] = (float)b;

    float dist[PPT];
#pragma unroll
    for (int i = 0; i < PPT; ++i) dist[i] = INFINITY;

    __syncthreads();

    int   cur = 0;
    float lx = xs[0], ly = ys[0], lz = zs[0];

    for (int s = 0; s < MM; ++s) {
        if (tid == 0) {
            samp[b * MM + s] = cur;
            centers_out[((size_t)b * MM + s) * 3 + 0] = lx;
            centers_out[((size_t)b * MM + s) * 3 + 1] = ly;
            centers_out[((size_t)b * MM + s) * 3 + 2] = lz;
        }
        if (s == MM - 1) break;   // last argmax unused by the reference

        float bv = -INFINITY;
        int   bi = 0x7fffffff;
#pragma unroll
        for (int i = 0; i < PPT; ++i) {
            // exact ref arithmetic: ((dx*dx + dy*dy) + dz*dz), no FMA contraction
            float dx = __fsub_rn(xs[tid + i * FT], lx);
            float dy = __fsub_rn(ys[tid + i * FT], ly);
            float dz = __fsub_rn(zs[tid + i * FT], lz);
            float d  = __fadd_rn(__fadd_rn(__fmul_rn(dx, dx), __fmul_rn(dy, dy)),
                                 __fmul_rn(dz, dz));
            float nd = fminf(dist[i], d);
            dist[i] = nd;
            // ascending index within thread + strict > == first-max tie-break
            if (nd > bv) { bv = nd; bi = tid + i * FT; }
        }

        // wave64 argmax via DPP; lane 63 ends with the wave winner
        DPP_ARGMAX_STEP(bv, bi, 0x111, 0xf);   // row_shr:1
        DPP_ARGMAX_STEP(bv, bi, 0x112, 0xf);   // row_shr:2
        DPP_ARGMAX_STEP(bv, bi, 0x114, 0xf);   // row_shr:4
        DPP_ARGMAX_STEP(bv, bi, 0x118, 0xf);   // row_shr:8
        DPP_ARGMAX_STEP(bv, bi, 0x142, 0xa);   // row_bcast:15 -> rows 1,3
        DPP_ARGMAX_STEP(bv, bi, 0x143, 0xc);   // row_bcast:31 -> rows 2,3

        const int par = s & 1;
        if (lane == 63) slots[par][wv] = make_float2(bv, __int_as_float(bi));
        __syncthreads();

        // vectorized scan of the 8 per-wave winners: tree of comparators
        const float2 s0 = slots[par][0], s1 = slots[par][1];
        const float2 s2 = slots[par][2], s3 = slots[par][3];
        const float2 s4 = slots[par][4], s5 = slots[par][5];
        const float2 s6 = slots[par][6], s7 = slots[par][7];
        const float2 a0 = argmax2(s0, s1), a1 = argmax2(s2, s3);
        const float2 a2 = argmax2(s4, s5), a3 = argmax2(s6, s7);
        const float2 b0 = argmax2(a0, a1), b1 = argmax2(a2, a3);
        const float2 win = argmax2(b0, b1);

        cur = __float_as_int(win.y);
        lx = xs[cur];
        ly = ys[cur];
        lz = zs[cur];
    }
}

// ---------------- Kernel 2: radius-KNN, one wave per center ----------------
#define CAP 256
__global__ __launch_bounds__(256) void knn_kernel(
    const float* __restrict__ pos,
    const int* __restrict__ samp,
    int* __restrict__ nbr,
    int* __restrict__ cntbuf)
{
    const int wave = threadIdx.x >> 6;
    const int lane = threadIdx.x & 63;
    const int c = blockIdx.x * 4 + wave;          // global center id
    const int b = c >> 11;                         // c / MM
    const float* pb = pos + (size_t)b * NN * 3;

    __shared__ float sd2[4][CAP];
    __shared__ int   sid[4][CAP];

    const int ctr = samp[c];
    const float cx = pb[ctr * 3 + 0];
    const float cy = pb[ctr * 3 + 1];
    const float cz = pb[ctr * 3 + 2];
    const float R2 = (float)(0.1 * 0.1);

    int cnt = 0;
    for (int r = 0; r < NN / 64; ++r) {
        const int g = r * 64 + lane;
        float dx = __fsub_rn(cx, pb[g * 3 + 0]);
        float dy = __fsub_rn(cy, pb[g * 3 + 1]);
        float dz = __fsub_rn(cz, pb[g * 3 + 2]);
        float d2 = __fadd_rn(__fadd_rn(__fmul_rn(dx, dx), __fmul_rn(dy, dy)),
                             __fmul_rn(dz, dz));
        const bool pred = (d2 <= R2);
        const unsigned long long mask = __ballot(pred);
        const int before = __popcll(mask & ((1ull << lane) - 1ull));
        if (pred) {
            const int slot = cnt + before;
            if (slot < CAP) { sd2[wave][slot] = d2; sid[wave][slot] = g; }
        }
        cnt += __popcll(mask);
    }
    if (cnt > CAP) cnt = CAP;
    __syncthreads();

    // rank-select the K smallest (tie -> lower point index) == lax.top_k set
    for (int ci = lane; ci < cnt; ci += 64) {
        const float dc = sd2[wave][ci];
        const int   ic = sid[wave][ci];
        int rank = 0;
        for (int j = 0; j < cnt; ++j) {
            const float dj = sd2[wave][j];
            const int   ij = sid[wave][j];
            rank += (dj < dc || (dj == dc && ij < ic)) ? 1 : 0;
        }
        if (rank < KK) nbr[c * KK + rank] = ic;
    }
    if (lane == 0) cntbuf[c] = (cnt < KK) ? cnt : KK;
}

// ---------------- Kernel 3: gather + MLP + max-pool, one wave per center ----
__global__ __launch_bounds__(256) void mlp_kernel(
    const float* __restrict__ x,
    const float* __restrict__ pos,
    const float* __restrict__ W1,
    const float* __restrict__ b1,
    const float* __restrict__ W2,
    const float* __restrict__ b2,
    const int* __restrict__ nbr,
    const int* __restrict__ cntbuf,
    const float* __restrict__ centers,
    float* __restrict__ out)
{
    __shared__ float WT[64 * 68];         // W1^T then W2^T (stride 68)
    __shared__ float featL[4][32 * 68];   // per-wave feat rows, later h1 rows

    const int tid = threadIdx.x, wave = tid >> 6, lane = tid & 63;
    const int c = blockIdx.x * 4 + wave;
    const int b = c >> 11;
    const int cnt = cntbuf[c];

    for (int idx = tid; idx < 67 * 64; idx += 256) {
        const int i = idx >> 6, h = idx & 63;
        WT[h * 68 + i] = W1[idx];
    }
    if (tid < 64) WT[tid * 68 + 67] = 0.0f;

    const float ctr0 = centers[c * 3 + 0];
    const float ctr1 = centers[c * 3 + 1];
    const float ctr2 = centers[c * 3 + 2];
    for (int k = 0; k < cnt; ++k) {
        const int j = nbr[c * KK + k];
        featL[wave][k * 68 + lane] = x[((size_t)b * NN + j) * FF + lane];
        if (lane < 3) {
            const float pj = pos[((size_t)b * NN + j) * 3 + lane];
            const float ci = (lane == 0) ? ctr0 : ((lane == 1) ? ctr1 : ctr2);
            featL[wave][k * 68 + 64 + lane] = __fsub_rn(pj, ci);
        }
        if (lane == 3) featL[wave][k * 68 + 67] = 0.0f;
    }
    __syncthreads();

    float w[68];
#pragma unroll
    for (int i4 = 0; i4 < 17; ++i4) {
        const float4 v = *(const float4*)&WT[lane * 68 + i4 * 4];
        w[i4 * 4 + 0] = v.x; w[i4 * 4 + 1] = v.y;
        w[i4 * 4 + 2] = v.z; w[i4 * 4 + 3] = v.w;
    }
    const float bias1 = b1[lane];
    for (int k = 0; k < cnt; ++k) {
        float acc = bias1;
#pragma unroll
        for (int i4 = 0; i4 < 17; ++i4) {
            const float4 f = *(const float4*)&featL[wave][k * 68 + i4 * 4];
            acc = fmaf(f.x, w[i4 * 4 + 0], acc);
            acc = fmaf(f.y, w[i4 * 4 + 1], acc);
            acc = fmaf(f.z, w[i4 * 4 + 2], acc);
            acc = fmaf(f.w, w[i4 * 4 + 3], acc);
        }
        featL[wave][k * 68 + lane] = fmaxf(acc, 0.0f);
    }
    __syncthreads();

    for (int idx = tid; idx < 64 * 64; idx += 256) {
        const int i = idx >> 6, h = idx & 63;
        WT[h * 68 + i] = W2[idx];
    }
    __syncthreads();

#pragma unroll
    for (int i4 = 0; i4 < 16; ++i4) {
        const float4 v = *(const float4*)&WT[lane * 68 + i4 * 4];
        w[i4 * 4 + 0] = v.x; w[i4 * 4 + 1] = v.y;
        w[i4 * 4 + 2] = v.z; w[i4 * 4 + 3] = v.w;
    }
    const float bias2 = b2[lane];
    float m = -INFINITY;
    for (int k = 0; k < cnt; ++k) {
        float acc = bias2;
#pragma unroll
        for (int i4 = 0; i4 < 16; ++i4) {
            const float4 f = *(const float4*)&featL[wave][k * 68 + i4 * 4];
            acc = fmaf(f.x, w[i4 * 4 + 0], acc);
            acc = fmaf(f.y, w[i4 * 4 + 1], acc);
            acc = fmaf(f.z, w[i4 * 4 + 2], acc);
            acc = fmaf(f.w, w[i4 * 4 + 3], acc);
        }
        m = fmaxf(m, fmaxf(acc, 0.0f));
    }
    out[(size_t)c * HH + lane] = (cnt > 0) ? m : 0.0f;
}

extern "C" void kernel_launch(void* const* d_in, const int* in_sizes, int n_in,
                              void* d_out, int out_size, void* d_ws, size_t ws_size,
                              hipStream_t stream) {
    const float* x   = (const float*)d_in[0];   // [B*N, 64]
    const float* pos = (const float*)d_in[1];   // [B*N, 3]
    const float* W1  = (const float*)d_in[3];   // [67, 64]
    const float* b1  = (const float*)d_in[4];   // [64]
    const float* W2  = (const float*)d_in[5];   // [64, 64]
    const float* b2  = (const float*)d_in[6];   // [64]

    float* out         = (float*)d_out;                      // [B*M, 64]
    float* centers_out = out + (size_t)NB * MM * HH;         // [B*M, 3]
    float* batch_out   = centers_out + (size_t)NB * MM * 3;  // [B*M]

    char* ws = (char*)d_ws;
    int* samp   = (int*)ws;                             // [B*M]
    int* cntbuf = (int*)(ws + (size_t)NB * MM * 4);     // [B*M]
    int* nbr    = (int*)(ws + (size_t)2 * NB * MM * 4); // [B*M, K]

    fps_kernel<<<NB, FT, 0, stream>>>(pos, samp, centers_out, batch_out);
    knn_kernel<<<(NB * MM) / 4, 256, 0, stream>>>(pos, samp, nbr, cntbuf);
    mlp_kernel<<<(NB * MM) / 4, 256, 0, stream>>>(x, pos, W1, b1, W2, b2,
                                                  nbr, cntbuf, centers_out, out);
}